// Round 1
// baseline (731.794 us; speedup 1.0000x reference)
//
#include <hip/hip_runtime.h>
#include <math.h>

// ---------------- structure kernels ----------------

__global__ void zero2_kernel(int* __restrict__ a, int* __restrict__ b, int n) {
  int i = blockIdx.x * blockDim.x + threadIdx.x;
  if (i < n) { a[i] = 0; b[i] = 0; }
}

__global__ void hist_kernel(const int* __restrict__ dst, int* __restrict__ cnt, int E) {
  int e = blockIdx.x * blockDim.x + threadIdx.x;
  if (e < E) atomicAdd(&cnt[dst[e]], 1);
}

__global__ void dis_kernel(const int* __restrict__ cnt, float* __restrict__ dis, int N) {
  int i = blockIdx.x * blockDim.x + threadIdx.x;
  if (i < N) dis[i] = 1.0f / sqrtf((float)(cnt[i] + 1));  // +1 self loop
}

__global__ void scan_block_kernel(const int* __restrict__ cnt, int* __restrict__ offs,
                                  int* __restrict__ part, int N) {
  __shared__ int sh[256];
  int t = threadIdx.x;
  int i = blockIdx.x * 256 + t;
  int v = (i < N) ? cnt[i] : 0;
  sh[t] = v;
  __syncthreads();
  for (int s = 1; s < 256; s <<= 1) {
    int add = (t >= s) ? sh[t - s] : 0;
    __syncthreads();
    sh[t] += add;
    __syncthreads();
  }
  if (i < N) offs[i] = sh[t] - v;        // exclusive
  if (t == 255) part[blockIdx.x] = sh[255];
}

__global__ void scan_part_kernel(int* __restrict__ part, int nb) {
  __shared__ int sh[512];
  int t = threadIdx.x;
  int v = (t < nb) ? part[t] : 0;
  sh[t] = v;
  __syncthreads();
  for (int s = 1; s < 512; s <<= 1) {
    int add = (t >= s) ? sh[t - s] : 0;
    __syncthreads();
    sh[t] += add;
    __syncthreads();
  }
  if (t < nb) part[t] = sh[t] - v;       // exclusive
}

__global__ void scan_add_kernel(int* __restrict__ offs, const int* __restrict__ part,
                                int N, int E) {
  int i = blockIdx.x * blockDim.x + threadIdx.x;
  if (i < N) offs[i] += part[blockIdx.x];
  if (i == N) offs[N] = E;               // total
}

__global__ void scatter_kernel(const int* __restrict__ src, const int* __restrict__ dst,
                               const float* __restrict__ dis, const int* __restrict__ offs,
                               int* __restrict__ cursor, int* __restrict__ csr_src,
                               float* __restrict__ csr_norm, int E) {
  int e = blockIdx.x * blockDim.x + threadIdx.x;
  if (e >= E) return;
  int d = dst[e], s = src[e];
  int pos = offs[d] + atomicAdd(&cursor[d], 1);
  csr_src[pos] = s;
  csr_norm[pos] = dis[s] * dis[d];
}

// ---------------- GEMM: C[N,64] = H[N,K] @ W[K,64] ----------------
// block = 256 threads, tile = 64 rows x 64 cols, thread = 2 rows x 8 cols.
// Hs padded to 65 -> conflict-free broadcast reads; Ws read as float4 (2-way, free).

template <int K>
__global__ __launch_bounds__(256) void gemm_kernel(const float* __restrict__ H,
                                                   const float* __restrict__ W,
                                                   float* __restrict__ C, int N) {
  __shared__ float Hs[64][65];
  __shared__ float Ws[K][64];
  const int t = threadIdx.x;
  const int rowBase = blockIdx.x * 64;
  for (int i = t; i < K * 64; i += 256) Ws[i >> 6][i & 63] = W[i];

  const int cg = t & 7, pr = t >> 3;
  const int c0 = cg * 8, r0 = pr * 2;
  float acc0[8] = {0.f, 0.f, 0.f, 0.f, 0.f, 0.f, 0.f, 0.f};
  float acc1[8] = {0.f, 0.f, 0.f, 0.f, 0.f, 0.f, 0.f, 0.f};

  for (int k0 = 0; k0 < K; k0 += 64) {
    __syncthreads();  // protect Hs reuse; also fences Ws load on first iter
    for (int i = t; i < 64 * 64; i += 256) {
      int r = i >> 6, kk = i & 63;
      int gr = rowBase + r;
      Hs[r][kk] = (gr < N) ? H[(long)gr * K + k0 + kk] : 0.f;
    }
    __syncthreads();
#pragma unroll 8
    for (int kk = 0; kk < 64; ++kk) {
      float h0 = Hs[r0][kk];
      float h1 = Hs[r0 + 1][kk];
      const float4 w0 = *reinterpret_cast<const float4*>(&Ws[k0 + kk][c0]);
      const float4 w1 = *reinterpret_cast<const float4*>(&Ws[k0 + kk][c0 + 4]);
      acc0[0] += h0 * w0.x; acc0[1] += h0 * w0.y; acc0[2] += h0 * w0.z; acc0[3] += h0 * w0.w;
      acc0[4] += h0 * w1.x; acc0[5] += h0 * w1.y; acc0[6] += h0 * w1.z; acc0[7] += h0 * w1.w;
      acc1[0] += h1 * w0.x; acc1[1] += h1 * w0.y; acc1[2] += h1 * w0.z; acc1[3] += h1 * w0.w;
      acc1[4] += h1 * w1.x; acc1[5] += h1 * w1.y; acc1[6] += h1 * w1.z; acc1[7] += h1 * w1.w;
    }
  }
  int gr0 = rowBase + r0;
  if (gr0 < N) {
    float4* o = reinterpret_cast<float4*>(&C[(long)gr0 * 64 + c0]);
    o[0] = make_float4(acc0[0], acc0[1], acc0[2], acc0[3]);
    o[1] = make_float4(acc0[4], acc0[5], acc0[6], acc0[7]);
  }
  if (gr0 + 1 < N) {
    float4* o = reinterpret_cast<float4*>(&C[(long)(gr0 + 1) * 64 + c0]);
    o[0] = make_float4(acc1[0], acc1[1], acc1[2], acc1[3]);
    o[1] = make_float4(acc1[4], acc1[5], acc1[6], acc1[7]);
  }
}

// ---------------- aggregation: out[d] = relu(sum_{s->d} T[s]*norm + T[d]*dis[d]^2 + b) ----
// one wave per dst node, lane = feature.

__global__ __launch_bounds__(256) void aggregate_kernel(
    const float* __restrict__ T, const int* __restrict__ csr_src,
    const float* __restrict__ csr_norm, const int* __restrict__ offs,
    const float* __restrict__ dis, const float* __restrict__ bias,
    float* __restrict__ O, int N) {
  int gid = blockIdx.x * blockDim.x + threadIdx.x;
  int d = gid >> 6;
  int lane = gid & 63;
  if (d >= N) return;
  float dd = dis[d];
  float acc = T[(long)d * 64 + lane] * (dd * dd);  // self loop
  float acc2 = 0.f;
  int beg = offs[d], end = offs[d + 1];
  int i = beg;
  for (; i + 1 < end; i += 2) {
    int s0 = csr_src[i];     float n0 = csr_norm[i];
    int s1 = csr_src[i + 1]; float n1 = csr_norm[i + 1];
    acc  += T[(long)s0 * 64 + lane] * n0;
    acc2 += T[(long)s1 * 64 + lane] * n1;
  }
  if (i < end) {
    int s0 = csr_src[i];
    acc += T[(long)s0 * 64 + lane] * csr_norm[i];
  }
  float v = acc + acc2 + bias[lane];
  O[(long)d * 64 + lane] = v > 0.f ? v : 0.f;
}

// ---------------- pooling ----------------

__global__ void logits_kernel(const float* __restrict__ clo, const float* __restrict__ Wc,
                              const float* __restrict__ bc, float* __restrict__ lb, int N) {
  int i = blockIdx.x * blockDim.x + threadIdx.x;
  if (i >= N) return;
  float s = bc[0];
#pragma unroll
  for (int k = 0; k < 8; ++k) s += clo[(long)i * 8 + k] * Wc[k];
  lb[i] = s;
}

// one block (256 thr) per graph. batch is sorted; binary-search the node range.
// g = sum_i softmax_i * h3_i   (counts factor cancels exactly), then 64->16->1 MLP.
__global__ __launch_bounds__(256) void pool_kernel(
    const float* __restrict__ h3, const float* __restrict__ lb,
    const int* __restrict__ batch, const float* __restrict__ Wa1,
    const float* __restrict__ ba1, const float* __restrict__ Wa2,
    const float* __restrict__ ba2, float* __restrict__ out, int N) {
  __shared__ int sLo, sHi;
  __shared__ float red[256];
  __shared__ float Vs[4][64];
  __shared__ float sse[4];
  __shared__ float gv[64];
  __shared__ float am[16];
  const int g = blockIdx.x;
  const int t = threadIdx.x;
  if (t == 0) {
    int lo = 0, hi = N;
    while (lo < hi) { int mid = (lo + hi) >> 1; if (batch[mid] < g) lo = mid + 1; else hi = mid; }
    sLo = lo;
    lo = 0; hi = N;
    while (lo < hi) { int mid = (lo + hi) >> 1; if (batch[mid] < g + 1) lo = mid + 1; else hi = mid; }
    sHi = lo;
  }
  __syncthreads();
  const int lo = sLo, hi = sHi;

  // segment max of logits
  float lm = -1e30f;
  for (int i = lo + t; i < hi; i += 256) lm = fmaxf(lm, lb[i]);
  red[t] = lm;
  __syncthreads();
  for (int s = 128; s > 0; s >>= 1) {
    if (t < s) red[t] = fmaxf(red[t], red[t + s]);
    __syncthreads();
  }
  const float m = red[0];

  // V[f] = sum e_i * h3[i][f] ; se = sum e_i
  const int f = t & 63, sub = t >> 6;
  float vacc = 0.f, seacc = 0.f;
  for (int i = lo + sub; i < hi; i += 4) {
    float e = expf(lb[i] - m);
    seacc += e;  // identical across lanes of this wave
    vacc += e * h3[(long)i * 64 + f];
  }
  Vs[sub][f] = vacc;
  if (f == 0) sse[sub] = seacc;
  __syncthreads();
  if (t < 64) {
    float se = sse[0] + sse[1] + sse[2] + sse[3];
    float v = Vs[0][f] + Vs[1][f] + Vs[2][f] + Vs[3][f];
    gv[f] = (se > 0.f) ? v / se : 0.f;  // empty graph -> 0 (matches ref)
  }
  __syncthreads();
  if (t < 16) {
    float a = ba1[t];
#pragma unroll
    for (int k2 = 0; k2 < 64; ++k2) a += gv[k2] * Wa1[k2 * 16 + t];
    am[t] = a > 0.f ? a : 0.f;
  }
  __syncthreads();
  if (t == 0) {
    float o = ba2[0];
#pragma unroll
    for (int j = 0; j < 16; ++j) o += am[j] * Wa2[j];
    out[g] = o;
  }
}

// ---------------- launcher ----------------

extern "C" void kernel_launch(void* const* d_in, const int* in_sizes, int n_in,
                              void* d_out, int out_size, void* d_ws, size_t ws_size,
                              hipStream_t stream) {
  const float* x   = (const float*)d_in[0];
  const float* clo = (const float*)d_in[1];
  const float* W1  = (const float*)d_in[2];
  const float* b1  = (const float*)d_in[3];
  const float* W2  = (const float*)d_in[4];
  const float* b2  = (const float*)d_in[5];
  const float* W3  = (const float*)d_in[6];
  const float* b3  = (const float*)d_in[7];
  const float* Wc  = (const float*)d_in[8];
  const float* bc  = (const float*)d_in[9];
  const float* Wa1 = (const float*)d_in[10];
  const float* ba1 = (const float*)d_in[11];
  const float* Wa2 = (const float*)d_in[12];
  const float* ba2 = (const float*)d_in[13];
  const int* edge  = (const int*)d_in[14];
  const int* batch = (const int*)d_in[15];
  float* out = (float*)d_out;

  const int N = in_sizes[15];        // 100000
  const int E = in_sizes[14] / 2;    // 1600000
  const int G = out_size;            // 256

  const int* src = edge;
  const int* dst = edge + E;

  // workspace carve (bump allocator, 256B aligned). Total ~92 MB.
  char* p = (char*)d_ws;
  auto alloc = [&](size_t bytes) -> char* {
    char* r = p;
    p += (bytes + 255) & ~(size_t)255;
    return r;
  };
  float* bufA     = (float*)alloc((size_t)N * 64 * sizeof(float));
  float* bufB     = (float*)alloc((size_t)N * 64 * sizeof(float));
  float* bufC     = (float*)alloc((size_t)N * 64 * sizeof(float));
  int*   cnt      = (int*)  alloc((size_t)N * sizeof(int));
  float* dis      = (float*)alloc((size_t)N * sizeof(float));
  int*   offs     = (int*)  alloc((size_t)(N + 1) * sizeof(int));
  int*   cursor   = (int*)  alloc((size_t)N * sizeof(int));
  int*   part     = (int*)  alloc(512 * sizeof(int));
  float* lb       = (float*)alloc((size_t)N * sizeof(float));
  int*   csr_src  = (int*)  alloc((size_t)E * sizeof(int));
  float* csr_norm = (float*)alloc((size_t)E * sizeof(float));
  (void)ws_size; (void)n_in;

  const int gE = (E + 255) / 256;
  const int gN = (N + 255) / 256;   // also = #scan blocks (must be <= 512)

  zero2_kernel<<<gN, 256, 0, stream>>>(cnt, cursor, N);
  hist_kernel<<<gE, 256, 0, stream>>>(dst, cnt, E);
  dis_kernel<<<gN, 256, 0, stream>>>(cnt, dis, N);
  scan_block_kernel<<<gN, 256, 0, stream>>>(cnt, offs, part, N);
  scan_part_kernel<<<1, 512, 0, stream>>>(part, gN);
  scan_add_kernel<<<gN, 256, 0, stream>>>(offs, part, N, E);
  scatter_kernel<<<gE, 256, 0, stream>>>(src, dst, dis, offs, cursor, csr_src, csr_norm, E);

  const int gGemm = (N + 63) / 64;
  const int gAgg  = (N * 64 + 255) / 256;

  gemm_kernel<128><<<gGemm, 256, 0, stream>>>(x, W1, bufA, N);
  aggregate_kernel<<<gAgg, 256, 0, stream>>>(bufA, csr_src, csr_norm, offs, dis, b1, bufB, N);
  gemm_kernel<64><<<gGemm, 256, 0, stream>>>(bufB, W2, bufA, N);
  aggregate_kernel<<<gAgg, 256, 0, stream>>>(bufA, csr_src, csr_norm, offs, dis, b2, bufC, N);
  gemm_kernel<64><<<gGemm, 256, 0, stream>>>(bufC, W3, bufA, N);
  aggregate_kernel<<<gAgg, 256, 0, stream>>>(bufA, csr_src, csr_norm, offs, dis, b3, bufB, N);

  logits_kernel<<<gN, 256, 0, stream>>>(clo, Wc, bc, lb, N);
  pool_kernel<<<G, 256, 0, stream>>>(bufB, lb, batch, Wa1, ba1, Wa2, ba2, out, N);
}

// Round 2
// 662.425 us; speedup vs baseline: 1.1047x; 1.1047x over previous
//
#include <hip/hip_runtime.h>
#include <math.h>

// ---------------- structure kernels ----------------

__global__ void hist_kernel(const int* __restrict__ dst, int* __restrict__ cnt, int E) {
  int e = blockIdx.x * blockDim.x + threadIdx.x;
  if (e < E) atomicAdd(&cnt[dst[e]], 1);
}

__global__ void dis_kernel(const int* __restrict__ cnt, float* __restrict__ dis, int N) {
  int i = blockIdx.x * blockDim.x + threadIdx.x;
  if (i < N) dis[i] = 1.0f / sqrtf((float)(cnt[i] + 1));  // +1 self loop
}

__global__ void scan_block_kernel(const int* __restrict__ cnt, int* __restrict__ offs,
                                  int* __restrict__ part, int N) {
  __shared__ int sh[256];
  int t = threadIdx.x;
  int i = blockIdx.x * 256 + t;
  int v = (i < N) ? cnt[i] : 0;
  sh[t] = v;
  __syncthreads();
  for (int s = 1; s < 256; s <<= 1) {
    int add = (t >= s) ? sh[t - s] : 0;
    __syncthreads();
    sh[t] += add;
    __syncthreads();
  }
  if (i < N) offs[i] = sh[t] - v;        // exclusive
  if (t == 255) part[blockIdx.x] = sh[255];
}

__global__ void scan_part_kernel(int* __restrict__ part, int nb) {
  __shared__ int sh[512];
  int t = threadIdx.x;
  int v = (t < nb) ? part[t] : 0;
  sh[t] = v;
  __syncthreads();
  for (int s = 1; s < 512; s <<= 1) {
    int add = (t >= s) ? sh[t - s] : 0;
    __syncthreads();
    sh[t] += add;
    __syncthreads();
  }
  if (t < nb) part[t] = sh[t] - v;       // exclusive
}

__global__ void scan_add_kernel(int* __restrict__ offs, const int* __restrict__ part, int N) {
  int i = blockIdx.x * blockDim.x + threadIdx.x;
  if (i < N) offs[i] += part[blockIdx.x];
}

// scatter: atomicAdd directly on offs -> after this kernel offs[d] == end(d)
// (exclusive prefix of d+1). csr_src holds source indices grouped by dst.
__global__ void scatter_kernel(const int* __restrict__ src, const int* __restrict__ dst,
                               int* __restrict__ offs, int* __restrict__ csr_src, int E) {
  int e = blockIdx.x * blockDim.x + threadIdx.x;
  if (e >= E) return;
  int d = dst[e];
  int pos = atomicAdd(&offs[d], 1);
  csr_src[pos] = src[e];
}

// ---------------- GEMM: C[N,64] = (H[N,K] @ W[K,64]) * dis[row] ----------------
// block = 256 threads, tile = 64 rows x 64 cols, thread = 2 rows x 8 cols.

template <int K>
__global__ __launch_bounds__(256) void gemm_kernel(const float* __restrict__ H,
                                                   const float* __restrict__ W,
                                                   const float* __restrict__ dis,
                                                   float* __restrict__ C, int N) {
  __shared__ float Hs[64][65];
  __shared__ float Ws[K][64];
  const int t = threadIdx.x;
  const int rowBase = blockIdx.x * 64;
  for (int i = t; i < K * 64; i += 256) Ws[i >> 6][i & 63] = W[i];

  const int cg = t & 7, pr = t >> 3;
  const int c0 = cg * 8, r0 = pr * 2;
  float acc0[8] = {0.f, 0.f, 0.f, 0.f, 0.f, 0.f, 0.f, 0.f};
  float acc1[8] = {0.f, 0.f, 0.f, 0.f, 0.f, 0.f, 0.f, 0.f};

  for (int k0 = 0; k0 < K; k0 += 64) {
    __syncthreads();  // protect Hs reuse; also fences Ws load on first iter
    for (int i = t; i < 64 * 64; i += 256) {
      int r = i >> 6, kk = i & 63;
      int gr = rowBase + r;
      Hs[r][kk] = (gr < N) ? H[(long)gr * K + k0 + kk] : 0.f;
    }
    __syncthreads();
#pragma unroll 8
    for (int kk = 0; kk < 64; ++kk) {
      float h0 = Hs[r0][kk];
      float h1 = Hs[r0 + 1][kk];
      const float4 w0 = *reinterpret_cast<const float4*>(&Ws[k0 + kk][c0]);
      const float4 w1 = *reinterpret_cast<const float4*>(&Ws[k0 + kk][c0 + 4]);
      acc0[0] += h0 * w0.x; acc0[1] += h0 * w0.y; acc0[2] += h0 * w0.z; acc0[3] += h0 * w0.w;
      acc0[4] += h0 * w1.x; acc0[5] += h0 * w1.y; acc0[6] += h0 * w1.z; acc0[7] += h0 * w1.w;
      acc1[0] += h1 * w0.x; acc1[1] += h1 * w0.y; acc1[2] += h1 * w0.z; acc1[3] += h1 * w0.w;
      acc1[4] += h1 * w1.x; acc1[5] += h1 * w1.y; acc1[6] += h1 * w1.z; acc1[7] += h1 * w1.w;
    }
  }
  int gr0 = rowBase + r0;
  if (gr0 < N) {
    float s = dis[gr0];
    float4* o = reinterpret_cast<float4*>(&C[(long)gr0 * 64 + c0]);
    o[0] = make_float4(acc0[0] * s, acc0[1] * s, acc0[2] * s, acc0[3] * s);
    o[1] = make_float4(acc0[4] * s, acc0[5] * s, acc0[6] * s, acc0[7] * s);
  }
  if (gr0 + 1 < N) {
    float s = dis[gr0 + 1];
    float4* o = reinterpret_cast<float4*>(&C[(long)(gr0 + 1) * 64 + c0]);
    o[0] = make_float4(acc1[0] * s, acc1[1] * s, acc1[2] * s, acc1[3] * s);
    o[1] = make_float4(acc1[4] * s, acc1[5] * s, acc1[6] * s, acc1[7] * s);
  }
}

// ---------------- aggregation ----------------
// Ts rows are pre-scaled by dis[src]. out[d] = relu(dis[d]*(Ts[d] + sum Ts[s]) + b)
// one wave per dst node, lane = feature; 4-way unrolled gather for ILP.

__global__ __launch_bounds__(256) void aggregate_kernel(
    const float* __restrict__ Ts, const int* __restrict__ csr_src,
    const int* __restrict__ ends, const float* __restrict__ dis,
    const float* __restrict__ bias, float* __restrict__ O, int N) {
  int gid = blockIdx.x * blockDim.x + threadIdx.x;
  int d = gid >> 6;
  int lane = gid & 63;
  if (d >= N) return;
  int beg = (d == 0) ? 0 : ends[d - 1];
  int end = ends[d];
  float a0 = Ts[(long)d * 64 + lane];  // self loop (pre-scaled by dis[d])
  float a1 = 0.f, a2 = 0.f, a3 = 0.f;
  int i = beg;
  for (; i + 3 < end; i += 4) {
    int s0 = csr_src[i];
    int s1 = csr_src[i + 1];
    int s2 = csr_src[i + 2];
    int s3 = csr_src[i + 3];
    a0 += Ts[(long)s0 * 64 + lane];
    a1 += Ts[(long)s1 * 64 + lane];
    a2 += Ts[(long)s2 * 64 + lane];
    a3 += Ts[(long)s3 * 64 + lane];
  }
  for (; i < end; ++i) a0 += Ts[(long)csr_src[i] * 64 + lane];
  float v = ((a0 + a1) + (a2 + a3)) * dis[d] + bias[lane];
  O[(long)d * 64 + lane] = v > 0.f ? v : 0.f;
}

// ---------------- pooling ----------------

__global__ void logits_kernel(const float* __restrict__ clo, const float* __restrict__ Wc,
                              const float* __restrict__ bc, float* __restrict__ lb, int N) {
  int i = blockIdx.x * blockDim.x + threadIdx.x;
  if (i >= N) return;
  float s = bc[0];
#pragma unroll
  for (int k = 0; k < 8; ++k) s += clo[(long)i * 8 + k] * Wc[k];
  lb[i] = s;
}

// one block (256 thr) per graph. batch is sorted; binary-search the node range.
// g = sum_i softmax_i * h3_i (counts factor cancels exactly), then 64->16->1 MLP.
__global__ __launch_bounds__(256) void pool_kernel(
    const float* __restrict__ h3, const float* __restrict__ lb,
    const int* __restrict__ batch, const float* __restrict__ Wa1,
    const float* __restrict__ ba1, const float* __restrict__ Wa2,
    const float* __restrict__ ba2, float* __restrict__ out, int N) {
  __shared__ int sLo, sHi;
  __shared__ float red[256];
  __shared__ float Vs[4][64];
  __shared__ float sse[4];
  __shared__ float gv[64];
  __shared__ float am[16];
  const int g = blockIdx.x;
  const int t = threadIdx.x;
  if (t == 0) {
    int lo = 0, hi = N;
    while (lo < hi) { int mid = (lo + hi) >> 1; if (batch[mid] < g) lo = mid + 1; else hi = mid; }
    sLo = lo;
    lo = 0; hi = N;
    while (lo < hi) { int mid = (lo + hi) >> 1; if (batch[mid] < g + 1) lo = mid + 1; else hi = mid; }
    sHi = lo;
  }
  __syncthreads();
  const int lo = sLo, hi = sHi;

  // segment max of logits
  float lm = -1e30f;
  for (int i = lo + t; i < hi; i += 256) lm = fmaxf(lm, lb[i]);
  red[t] = lm;
  __syncthreads();
  for (int s = 128; s > 0; s >>= 1) {
    if (t < s) red[t] = fmaxf(red[t], red[t + s]);
    __syncthreads();
  }
  const float m = red[0];

  // V[f] = sum e_i * h3[i][f] ; se = sum e_i
  const int f = t & 63, sub = t >> 6;
  float vacc = 0.f, seacc = 0.f;
  for (int i = lo + sub; i < hi; i += 4) {
    float e = expf(lb[i] - m);
    seacc += e;  // identical across lanes of this wave
    vacc += e * h3[(long)i * 64 + f];
  }
  Vs[sub][f] = vacc;
  if (f == 0) sse[sub] = seacc;
  __syncthreads();
  if (t < 64) {
    float se = sse[0] + sse[1] + sse[2] + sse[3];
    float v = Vs[0][f] + Vs[1][f] + Vs[2][f] + Vs[3][f];
    gv[f] = (se > 0.f) ? v / se : 0.f;  // empty graph -> 0 (matches ref)
  }
  __syncthreads();
  if (t < 16) {
    float a = ba1[t];
#pragma unroll
    for (int k2 = 0; k2 < 64; ++k2) a += gv[k2] * Wa1[k2 * 16 + t];
    am[t] = a > 0.f ? a : 0.f;
  }
  __syncthreads();
  if (t == 0) {
    float o = ba2[0];
#pragma unroll
    for (int j = 0; j < 16; ++j) o += am[j] * Wa2[j];
    out[g] = o;
  }
}

// ---------------- launcher ----------------

extern "C" void kernel_launch(void* const* d_in, const int* in_sizes, int n_in,
                              void* d_out, int out_size, void* d_ws, size_t ws_size,
                              hipStream_t stream) {
  const float* x   = (const float*)d_in[0];
  const float* clo = (const float*)d_in[1];
  const float* W1  = (const float*)d_in[2];
  const float* b1  = (const float*)d_in[3];
  const float* W2  = (const float*)d_in[4];
  const float* b2  = (const float*)d_in[5];
  const float* W3  = (const float*)d_in[6];
  const float* b3  = (const float*)d_in[7];
  const float* Wc  = (const float*)d_in[8];
  const float* bc  = (const float*)d_in[9];
  const float* Wa1 = (const float*)d_in[10];
  const float* ba1 = (const float*)d_in[11];
  const float* Wa2 = (const float*)d_in[12];
  const float* ba2 = (const float*)d_in[13];
  const int* edge  = (const int*)d_in[14];
  const int* batch = (const int*)d_in[15];
  float* out = (float*)d_out;

  const int N = in_sizes[15];        // 100000
  const int E = in_sizes[14] / 2;    // 1600000
  const int G = out_size;            // 256

  const int* src = edge;
  const int* dst = edge + E;

  // workspace carve (bump allocator, 256B aligned).
  char* p = (char*)d_ws;
  auto alloc = [&](size_t bytes) -> char* {
    char* r = p;
    p += (bytes + 255) & ~(size_t)255;
    return r;
  };
  float* bufA     = (float*)alloc((size_t)N * 64 * sizeof(float));
  float* bufB     = (float*)alloc((size_t)N * 64 * sizeof(float));
  int*   cnt      = (int*)  alloc((size_t)N * sizeof(int));
  float* dis      = (float*)alloc((size_t)N * sizeof(float));
  int*   offs     = (int*)  alloc((size_t)N * sizeof(int));
  int*   part     = (int*)  alloc(512 * sizeof(int));
  float* lb       = (float*)alloc((size_t)N * sizeof(float));
  int*   csr_src  = (int*)  alloc((size_t)E * sizeof(int));
  (void)ws_size; (void)n_in;

  const int gE = (E + 255) / 256;
  const int gN = (N + 255) / 256;   // also = #scan blocks (must be <= 512)

  hipMemsetAsync(cnt, 0, (size_t)N * sizeof(int), stream);
  hist_kernel<<<gE, 256, 0, stream>>>(dst, cnt, E);
  dis_kernel<<<gN, 256, 0, stream>>>(cnt, dis, N);
  scan_block_kernel<<<gN, 256, 0, stream>>>(cnt, offs, part, N);
  scan_part_kernel<<<1, 512, 0, stream>>>(part, gN);
  scan_add_kernel<<<gN, 256, 0, stream>>>(offs, part, N);
  scatter_kernel<<<gE, 256, 0, stream>>>(src, dst, offs, csr_src, E);
  // after scatter: offs[d] == end offset of node d's CSR segment

  const int gGemm = (N + 63) / 64;
  const int gAgg  = (N * 64 + 255) / 256;

  gemm_kernel<128><<<gGemm, 256, 0, stream>>>(x, W1, dis, bufA, N);
  aggregate_kernel<<<gAgg, 256, 0, stream>>>(bufA, csr_src, offs, dis, b1, bufB, N);
  gemm_kernel<64><<<gGemm, 256, 0, stream>>>(bufB, W2, dis, bufA, N);
  aggregate_kernel<<<gAgg, 256, 0, stream>>>(bufA, csr_src, offs, dis, b2, bufB, N);
  gemm_kernel<64><<<gGemm, 256, 0, stream>>>(bufB, W3, dis, bufA, N);
  aggregate_kernel<<<gAgg, 256, 0, stream>>>(bufA, csr_src, offs, dis, b3, bufB, N);

  logits_kernel<<<gN, 256, 0, stream>>>(clo, Wc, bc, lb, N);
  pool_kernel<<<G, 256, 0, stream>>>(bufB, lb, batch, Wa1, ba1, Wa2, ba2, out, N);
}